// Round 10
// baseline (283.272 us; speedup 1.0000x reference)
//
#include <hip/hip_runtime.h>

// ---------------------------------------------------------------------------
// CasualMultiQueryAttention: x->(Q,K,V) proj + RoPE, causal flash attention,
// output projection. B=2,S=2048,D=2048,H=16,HD=128. bf16 MFMA compute.
// R10: gemm engine single-region K-tiles: {stage(t+2); vmcnt(6); barrier;
//      16 ds_read + 32 MFMA compiler-interleaved (counted lgkmcnt); barrier}.
//      R9 diagnosis: barrier pair serialized {VALU addr + ds_read drain}
//      (~1000 cyc) against the 620-cyc MFMA window -> 33.6% util. Ring via
//      rotating named pointers (no runtime-indexed arrays, rule #20).
//      Attention/convert/fallback identical to R7-R9 (proven).
// ---------------------------------------------------------------------------

typedef __attribute__((ext_vector_type(8))) short short8;
typedef __attribute__((ext_vector_type(4))) float f32x4;
typedef __attribute__((ext_vector_type(16))) float f32x16;
typedef __attribute__((ext_vector_type(2))) unsigned short u16x2;
typedef __attribute__((ext_vector_type(4))) unsigned short u16x4;
typedef __attribute__((ext_vector_type(8))) unsigned short u16x8;

constexpr int Bc = 2, Sc = 2048, Dc = 2048, Hc = 16, HDc = 128;
constexpr int Mc = Bc * Sc;            // 4096 rows
constexpr int Nc = Dc, Kc = Dc;        // 2048
constexpr int NT = Kc / 64;            // 32 K-tiles
constexpr float QSCL = 0.08838834764831845f * 1.4426950408889634f; // 1/sqrt(HD)*log2e

__device__ __forceinline__ unsigned short f2bf(float f) {
    union { float f; unsigned u; } x; x.f = f;
    unsigned r = x.u + 0x7FFFu + ((x.u >> 16) & 1u);   // RNE
    return (unsigned short)(r >> 16);
}
__device__ __forceinline__ float bf2f(unsigned short u) {
    union { float f; unsigned u; } x; x.u = (unsigned)u << 16; return x.f;
}

__device__ __forceinline__ void g2lds16(const void* g, void* l) {
    __builtin_amdgcn_global_load_lds(
        (const __attribute__((address_space(1))) void*)g,
        (__attribute__((address_space(3))) void*)l, 16, 0, 0);
}

// --------------------------- fp32 -> bf16 convert ---------------------------
__device__ __forceinline__ void cvt_body(const float* __restrict__ in,
                                         unsigned short* __restrict__ out, int i) {
    f32x4 a = *((const f32x4*)in + (size_t)i * 2);
    f32x4 b = *((const f32x4*)in + (size_t)i * 2 + 1);
    u16x8 o;
    o[0] = f2bf(a[0]); o[1] = f2bf(a[1]); o[2] = f2bf(a[2]); o[3] = f2bf(a[3]);
    o[4] = f2bf(b[0]); o[5] = f2bf(b[1]); o[6] = f2bf(b[2]); o[7] = f2bf(b[3]);
    *((u16x8*)out + i) = o;
}

__global__ __launch_bounds__(256) void cvt_f32_bf16(
    const float* __restrict__ in, unsigned short* __restrict__ out, int n8) {
    int i = blockIdx.x * 256 + threadIdx.x;
    if (i >= n8) return;
    cvt_body(in, out, i);
}

__global__ __launch_bounds__(256) void cvt_batch(
    const float* __restrict__ x,  unsigned short* __restrict__ xo,
    const float* __restrict__ w0, unsigned short* __restrict__ o0,
    const float* __restrict__ w1, unsigned short* __restrict__ o1,
    const float* __restrict__ w2, unsigned short* __restrict__ o2,
    const float* __restrict__ w3, unsigned short* __restrict__ o3) {
    const int which = blockIdx.y;
    const float* in; unsigned short* out; int n8;
    if (which == 0)      { in = x;  out = xo; n8 = (Mc * Dc) / 8; }
    else if (which == 1) { in = w0; out = o0; n8 = (Dc * Dc) / 8; }
    else if (which == 2) { in = w1; out = o1; n8 = (Dc * Dc) / 8; }
    else if (which == 3) { in = w2; out = o2; n8 = (Dc * Dc) / 8; }
    else                 { in = w3; out = o3; n8 = (Dc * Dc) / 8; }
    int i = blockIdx.x * 256 + threadIdx.x;
    if (i >= n8) return;
    cvt_body(in, out, i);
}

// ------------------ 8-wave single-region GEMM (256x128, ring-3) --------------
// KIND 0: fused QKV. A[4096][2048]*Wqkv[6144][2048]^T; mode=n0>>11 selects
//         epilogue: 0 RoPE->q (QSCL), 1 RoPE->k, 2 ->V^T [B][D][S].
// KIND 1: out-proj. A=attn out; epilogue fp32 + bias -> oq (float*).
#define G10_STAGE_A(tt, dst, ii) {                                             \
    int s_ = (ii) * 512 + tid, row_ = s_ >> 3, c_ = s_ & 7;                    \
    g2lds16(A + (size_t)(m0 + row_) * Kc + (tt) * 64 + ((c_ ^ (row_ & 7)) << 3), \
            (unsigned short*)(dst) + ((ii) * 512 + (w << 6)) * 8); }
#define G10_STAGE_B(tt, dst, ii) {                                             \
    int s_ = (ii) * 512 + tid, row_ = s_ >> 3, c_ = s_ & 7;                    \
    g2lds16(W + (size_t)(n0 + row_) * Kc + (tt) * 64 + ((c_ ^ (row_ & 7)) << 3), \
            (unsigned short*)(dst) + ((ii) * 512 + (w << 6)) * 8); }
#define G10_RDA(src, kk, f) { _Pragma("unroll")                                \
    for (int i = 0; i < 4; ++i) {                                              \
        int ra = wm * 64 + i * 16 + lrow;                                      \
        f[i] = *(const short8*)&(src)[ra * 64 + ((((kk)*4 + lhi) ^ (ra & 7)) << 3)]; } }
#define G10_RDB(src, kk, f) { _Pragma("unroll")                                \
    for (int j = 0; j < 4; ++j) {                                              \
        int rb = wn * 64 + j * 16 + lrow;                                      \
        f[j] = *(const short8*)&(src)[rb * 64 + ((((kk)*4 + lhi) ^ (rb & 7)) << 3)]; } }
#define G10_MFMA16(fa, fb) { _Pragma("unroll")                                 \
    for (int i = 0; i < 4; ++i)                                                \
        _Pragma("unroll")                                                      \
        for (int j = 0; j < 4; ++j)                                            \
            acc[i][j] = __builtin_amdgcn_mfma_f32_16x16x32_bf16(fa[i], fb[j], acc[i][j], 0, 0, 0); }

template <int KIND>
__global__ __launch_bounds__(512, 2) void gemm10(
    const unsigned short* __restrict__ A, const unsigned short* __restrict__ W,
    const float* __restrict__ bq, const float* __restrict__ bk,
    const float* __restrict__ bv, const float* __restrict__ rc,
    const float* __restrict__ rs, void* __restrict__ oq,
    unsigned short* __restrict__ ok, unsigned short* __restrict__ ov) {
    __shared__ __align__(16) unsigned short As[3][256 * 64];   // 96 KB
    __shared__ __align__(16) unsigned short Bs[3][128 * 64];   // 48 KB
    const int tid = threadIdx.x;
    const int w = tid >> 6, l = tid & 63;
    const int wm = w >> 1, wn = w & 1;            // 4M x 2N waves
    const int lrow = l & 15, lhi = l >> 4;
    const int m0 = blockIdx.y * 256, n0 = blockIdx.x * 128;

    f32x4 acc[4][4];
#pragma unroll
    for (int i = 0; i < 4; ++i)
#pragma unroll
        for (int j = 0; j < 4; ++j) acc[i][j] = (f32x4){0.f, 0.f, 0.f, 0.f};

    // ring pointers: rd = tile t, n1 = tile t+1, st = tile t+2 (stage target)
    const unsigned short *Ard = As[0], *An1 = As[1], *Ast = As[2];
    const unsigned short *Brd = Bs[0], *Bn1 = Bs[1], *Bst = Bs[2];

    // prologue: stage tiles 0,1 (per tile: A x4 rounds + B x2 rounds = 6 loads)
#pragma unroll
    for (int ii = 0; ii < 4; ++ii) G10_STAGE_A(0, Ard, ii);
    G10_STAGE_B(0, Brd, 0); G10_STAGE_B(0, Brd, 1);
#pragma unroll
    for (int ii = 0; ii < 4; ++ii) G10_STAGE_A(1, An1, ii);
    G10_STAGE_B(1, Bn1, 0); G10_STAGE_B(1, Bn1, 1);
    asm volatile("s_waitcnt vmcnt(6)" ::: "memory");   // tile 0 landed
    __builtin_amdgcn_s_barrier();

    short8 a0f[4], b0f[4], a1f[4], b1f[4];
    for (int t = 0; t < NT; ++t) {
        if (t + 2 < NT) {
#pragma unroll
            for (int ii = 0; ii < 4; ++ii) G10_STAGE_A(t + 2, Ast, ii);
            G10_STAGE_B(t + 2, Bst, 0); G10_STAGE_B(t + 2, Bst, 1);
            asm volatile("s_waitcnt vmcnt(6)" ::: "memory");   // t+1 landed
        } else {
            asm volatile("s_waitcnt vmcnt(0)" ::: "memory");
        }
        __builtin_amdgcn_s_barrier();
        // 16 ds_read + 32 MFMA in one region: compiler interleaves with
        // counted lgkmcnt; kk=1 reads complete under kk=0 MFMAs.
        G10_RDA(Ard, 0, a0f); G10_RDB(Brd, 0, b0f);
        G10_RDA(Ard, 1, a1f); G10_RDB(Brd, 1, b1f);
        __builtin_amdgcn_s_setprio(1);
        G10_MFMA16(a0f, b0f);
        G10_MFMA16(a1f, b1f);
        __builtin_amdgcn_s_setprio(0);
        __builtin_amdgcn_s_barrier();      // slot t%3 free for stage at t+1
        const unsigned short* ta = Ard; Ard = An1; An1 = Ast; Ast = ta;
        const unsigned short* tb = Brd; Brd = Bn1; Bn1 = Bst; Bst = tb;
    }

    // ---- epilogue ----
    const int mode = (KIND == 1) ? 3 : (n0 >> 11);   // uniform per block
    const float* bias = (KIND == 1) ? bq : (mode == 0 ? bq : mode == 1 ? bk : bv);
#pragma unroll
    for (int i = 0; i < 4; ++i) {
#pragma unroll
        for (int j = 0; j < 4; ++j) {
            int gm0 = m0 + wm * 64 + i * 16 + lhi * 4;
            int gn  = n0 + wn * 64 + j * 16 + lrow;
            int gnl = gn & (Dc - 1);
            float bvv = bias[gnl];
            if (mode == 0 || mode == 1) {
                unsigned short* o = (unsigned short*)(mode == 0 ? oq : (void*)ok);
                int fi = (gn & (HDc - 1)) >> 1;
#pragma unroll
                for (int rr = 0; rr < 4; ++rr) {
                    int gm = gm0 + rr;
                    float v = acc[i][j][rr] + bvv;
                    float p = __shfl_xor(v, 1);          // partner column gn^1
                    int pos = gm & (Sc - 1);
                    float cz = rc[pos * (HDc / 2) + fi];
                    float sz = rs[pos * (HDc / 2) + fi];
                    float ovv = (gn & 1) ? (p * sz + v * cz) : (v * cz - p * sz);
                    if (mode == 0) ovv *= QSCL;
                    o[(size_t)gm * Dc + gnl] = f2bf(ovv);
                }
            } else if (mode == 2) {
                int b = gm0 >> 11, sb = gm0 & (Sc - 1);
                u16x4 pk;
#pragma unroll
                for (int rr = 0; rr < 4; ++rr) pk[rr] = f2bf(acc[i][j][rr] + bvv);
                *(u16x4*)&ov[((size_t)b * Dc + gnl) * Sc + sb] = pk;
            } else {
                float* o = (float*)oq;
#pragma unroll
                for (int rr = 0; rr < 4; ++rr)
                    o[(size_t)(gm0 + rr) * Nc + gn] = acc[i][j][rr] + bvv;
            }
        }
    }
}

// --------------------------- legacy 128^2 GEMM (fallback path) ---------------
template <int MODE>
__global__ __launch_bounds__(256) void gemm_nt(
    const unsigned short* __restrict__ A, const unsigned short* __restrict__ W,
    const float* __restrict__ bias, const float* __restrict__ rc,
    const float* __restrict__ rs, void* __restrict__ outp) {
    __shared__ __align__(16) unsigned short As[128 * 64];
    __shared__ __align__(16) unsigned short Bs[128 * 64];
    const int tid = threadIdx.x;
    const int w = tid >> 6, l = tid & 63;
    const int wm = w >> 1, wn = w & 1;
    const int lrow = l & 15, lhi = l >> 4;
    const int m0 = blockIdx.y * 128, n0 = blockIdx.x * 128;

    f32x4 acc[4][4];
#pragma unroll
    for (int i = 0; i < 4; ++i)
#pragma unroll
        for (int j = 0; j < 4; ++j) acc[i][j] = (f32x4){0.f, 0.f, 0.f, 0.f};

    for (int k0 = 0; k0 < Kc; k0 += 64) {
        __syncthreads();
#pragma unroll
        for (int i = 0; i < 4; ++i) {
            int s = i * 256 + tid;
            int row = s >> 3, c = s & 7;
            int cg = (c ^ (row & 7)) * 8;
            g2lds16(A + (size_t)(m0 + row) * Kc + k0 + cg,
                    &As[(size_t)(i * 256 + (w << 6)) * 8]);
            g2lds16(W + (size_t)(n0 + row) * Kc + k0 + cg,
                    &Bs[(size_t)(i * 256 + (w << 6)) * 8]);
        }
        __syncthreads();
#pragma unroll
        for (int kk = 0; kk < 2; ++kk) {
            short8 af[4], bf[4];
#pragma unroll
            for (int i = 0; i < 4; ++i) {
                int ra = wm * 64 + i * 16 + lrow;
                af[i] = *(const short8*)&As[ra * 64 + (((kk * 4 + lhi) ^ (ra & 7)) << 3)];
                int rb = wn * 64 + i * 16 + lrow;
                bf[i] = *(const short8*)&Bs[rb * 64 + (((kk * 4 + lhi) ^ (rb & 7)) << 3)];
            }
#pragma unroll
            for (int i = 0; i < 4; ++i)
#pragma unroll
                for (int j = 0; j < 4; ++j)
                    acc[i][j] = __builtin_amdgcn_mfma_f32_16x16x32_bf16(
                        af[i], bf[j], acc[i][j], 0, 0, 0);
        }
    }

#pragma unroll
    for (int i = 0; i < 4; ++i) {
#pragma unroll
        for (int j = 0; j < 4; ++j) {
            int gm0 = m0 + wm * 64 + i * 16 + lhi * 4;
            int gn  = n0 + wn * 64 + j * 16 + lrow;
            float bv = bias[gn];
            if (MODE == 0 || MODE == 1) {
                unsigned short* o = (unsigned short*)outp;
                int fi = (gn & (HDc - 1)) >> 1;
#pragma unroll
                for (int r = 0; r < 4; ++r) {
                    int gm = gm0 + r;
                    float v = acc[i][j][r] + bv;
                    float p = __shfl_xor(v, 1);
                    int pos = gm & (Sc - 1);
                    float cz = rc[pos * (HDc / 2) + fi];
                    float sz = rs[pos * (HDc / 2) + fi];
                    float ov = (gn & 1) ? (p * sz + v * cz) : (v * cz - p * sz);
                    if (MODE == 0) ov *= QSCL;
                    o[(size_t)gm * Nc + gn] = f2bf(ov);
                }
            } else if (MODE == 2) {
                unsigned short* o = (unsigned short*)outp;
                int b = gm0 >> 11, sb = gm0 & (Sc - 1);
                u16x4 pk;
#pragma unroll
                for (int r = 0; r < 4; ++r) pk[r] = f2bf(acc[i][j][r] + bv);
                *(u16x4*)&o[((size_t)b * Dc + gn) * Sc + sb] = pk;
            } else {
                float* o = (float*)outp;
#pragma unroll
                for (int r = 0; r < 4; ++r)
                    o[(size_t)(gm0 + r) * Nc + gn] = acc[i][j][r] + bv;
            }
        }
    }
}

// ---------------- shared attention macros (proven R5 body) -------------------
#define ATTN_STAGE(tt, kd, vd) {                                               \
    const unsigned short* Kt = Kbase + (size_t)(tt) * 64 * Dc;                 \
    const unsigned short* Vp = Vbase + (tt) * 64;                              \
    _Pragma("unroll")                                                          \
    for (int i_ = 0; i_ < 4; ++i_) {                                           \
        int p_ = i_ * 256 + tid;                                               \
        int rK = p_ >> 4, sK = p_ & 15;                                        \
        g2lds16(Kt + (size_t)rK * Dc + ((sK ^ (rK & 15)) << 3),                \
                (kd) + (i_ * 256 + (w << 6)) * 8);                             \
        int rV = p_ >> 3, sV = p_ & 7;                                         \
        g2lds16(Vp + (size_t)rV * Sc + ((sV ^ (rV & 7)) << 3),                 \
                (vd) + (i_ * 256 + (w << 6)) * 8);                             \
    } }

#define ATTN_PVSTEP(PC, HB, KS) {                                              \
    int X0, X1, Y0, Y1;                                                        \
    asm("v_cvt_pk_bf16_f32 %0, %1, %2" : "=v"(X0) : "v"(PC[HB+0]), "v"(PC[HB+1])); \
    asm("v_cvt_pk_bf16_f32 %0, %1, %2" : "=v"(X1) : "v"(PC[HB+2]), "v"(PC[HB+3])); \
    asm("v_cvt_pk_bf16_f32 %0, %1, %2" : "=v"(Y0) : "v"(PC[HB+4]), "v"(PC[HB+5])); \
    asm("v_cvt_pk_bf16_f32 %0, %1, %2" : "=v"(Y1) : "v"(PC[HB+6]), "v"(PC[HB+7])); \
    asm("v_permlane32_swap_b32 %0, %1" : "+v"(X0), "+v"(Y0));                  \
    asm("v_permlane32_swap_b32 %0, %1" : "+v"(X1), "+v"(Y1));                  \
    union { int i[4]; short8 s; } pf_;                                         \
    pf_.i[0] = X0; pf_.i[1] = X1; pf_.i[2] = Y0; pf_.i[3] = Y1;                \
    _Pragma("unroll")                                                          \
    for (int dc_ = 0; dc_ < 4; ++dc_) {                                        \
        int rr = 32 * dc_ + ql;                                                \
        short8 vf = *(const short8*)&Vbuf[rr * 64 + (((2*(KS)+Hh) ^ (rr & 7)) << 3)]; \
        accv[dc_] = __builtin_amdgcn_mfma_f32_32x32x16_bf16(vf, pf_.s, accv[dc_], 0, 0, 0); \
    } }

#define ATTN_TILE_BODY(Kbuf, Vbuf, kb0)                                        \
    {                                                                          \
        f32x16 a0 = (f32x16)(0.f), a1 = (f32x16)(0.f);                         \
        __builtin_amdgcn_s_setprio(1);                                         \
        _Pragma("unroll")                                                      \
        for (int dc = 0; dc < 8; ++dc) {                                       \
            int r0 = ql, r1 = 32 + ql, sl = dc * 2 + Hh;                       \
            short8 k0 = *(const short8*)&Kbuf[r0 * 128 + ((sl ^ (r0 & 15)) << 3)]; \
            short8 k1 = *(const short8*)&Kbuf[r1 * 128 + ((sl ^ (r1 & 15)) << 3)]; \
            a0 = __builtin_amdgcn_mfma_f32_32x32x16_bf16(k0, qf[dc], a0, 0, 0, 0); \
            a1 = __builtin_amdgcn_mfma_f32_32x32x16_bf16(k1, qf[dc], a1, 0, 0, 0); \
        }                                                                      \
        __builtin_amdgcn_s_setprio(0);                                         \
        if ((kb0) >= 2 * qt * 64) {                                            \
            _Pragma("unroll")                                                  \
            for (int r = 0; r < 16; ++r) {                                     \
                int kl = (r & 3) + 8 * (r >> 2) + 4 * Hh;                      \
                if ((kb0) + kl > qg)      a0[r] = -3.0e38f;                    \
                if ((kb0) + 32 + kl > qg) a1[r] = -3.0e38f;                    \
            }                                                                  \
        }                                                                      \
        float m8[8];                                                           \
        _Pragma("unroll")                                                      \
        for (int r = 0; r < 8; ++r)                                            \
            m8[r] = fmaxf(fmaxf(a0[r], a0[r + 8]), fmaxf(a1[r], a1[r + 8]));   \
        float m4a = fmaxf(m8[0], m8[1]), m4b = fmaxf(m8[2], m8[3]);            \
        float m4c = fmaxf(m8[4], m8[5]), m4d = fmaxf(m8[6], m8[7]);            \
        float pm = fmaxf(fmaxf(m4a, m4b), fmaxf(m4c, m4d));                    \
        pm = fmaxf(pm, __shfl_xor(pm, 32));                                    \
        if (!__all(pm - mrun <= 8.0f)) {                                       \
            float mnew = fmaxf(mrun, pm);                                      \
            float fs = exp2f(mrun - mnew);                                     \
            mrun = mnew;                                                       \
            lrun *= fs;                                                        \
            _Pragma("unroll")                                                  \
            for (int dc = 0; dc < 4; ++dc)                                     \
                _Pragma("unroll")                                              \
                for (int r = 0; r < 16; ++r) accv[dc][r] *= fs;                \
        }                                                                      \
        float p0[16], p1[16];                                                  \
        _Pragma("unroll")                                                      \
        for (int r = 0; r < 16; ++r) p0[r] = exp2f(a0[r] - mrun);              \
        _Pragma("unroll")                                                      \
        for (int r = 0; r < 16; ++r) p1[r] = exp2f(a1[r] - mrun);              \
        float s8[8];                                                           \
        _Pragma("unroll")                                                      \
        for (int r = 0; r < 8; ++r)                                            \
            s8[r] = (p0[r] + p0[r + 8]) + (p1[r] + p1[r + 8]);                 \
        float s4a = s8[0] + s8[1], s4b = s8[2] + s8[3];                        \
        float s4c = s8[4] + s8[5], s4d = s8[6] + s8[7];                        \
        float ps = (s4a + s4b) + (s4c + s4d);                                  \
        lrun += ps + __shfl_xor(ps, 32);                                       \
        __builtin_amdgcn_s_setprio(1);                                         \
        ATTN_PVSTEP(p0, 0, 0); ATTN_PVSTEP(p0, 8, 1);                          \
        ATTN_PVSTEP(p1, 0, 2); ATTN_PVSTEP(p1, 8, 3);                          \
        __builtin_amdgcn_s_setprio(0);                                         \
    }

// --------------------------- attn: balanced KV-split part --------------------
__global__ __launch_bounds__(256, 2) void attn_part(
    const unsigned short* __restrict__ Q, const unsigned short* __restrict__ Kb,
    const unsigned short* __restrict__ Vt, unsigned short* __restrict__ O,
    unsigned short* __restrict__ pacc, float* __restrict__ pml) {
    __shared__ __align__(16) unsigned short Ks[2][64 * 128];
    __shared__ __align__(16) unsigned short Vs[2][128 * 64];
    const int tid = threadIdx.x;
    const int w = tid >> 6, l = tid & 63;
    const int ql = l & 31, Hh = l >> 5;
    const int bh = blockIdx.x;
    const int slot = blockIdx.y;
    int qt, part, np;
    if (slot < 16) { qt = 15 - (slot >> 1); part = slot & 1; np = 2; }
    else           { qt = 23 - slot;        part = 0;        np = 1; }
    const int nt   = 2 * qt + 2;
    const int tbeg = part ? (qt + 1) : 0;
    const int tend = (np == 2 && part == 0) ? (qt + 1) : nt;
    const int b = bh >> 4, h = bh & 15;

    const unsigned short* Kbase = Kb + ((size_t)b * Sc) * Dc + h * HDc;
    const unsigned short* Vbase = Vt + ((size_t)b * Dc + h * HDc) * Sc;

    const int qw0 = qt * 128 + w * 32;
    const int qg = qw0 + ql;

    short8 qf[8];
    {
        const unsigned short* qp = Q + ((size_t)(b * Sc + qg)) * Dc + h * HDc;
#pragma unroll
        for (int dc = 0; dc < 8; ++dc)
            qf[dc] = *(const short8*)(qp + dc * 16 + Hh * 8);
    }
    f32x16 accv[4];
#pragma unroll
    for (int i = 0; i < 4; ++i) accv[i] = (f32x16)(0.f);
    float mrun = -3.0e38f, lrun = 0.f;

    ATTN_STAGE(tbeg, Ks[0], Vs[0]);
    for (int t = tbeg; t < tend; ++t) {
        const int cur = (t - tbeg) & 1;
        if (t + 1 < tend) {
            ATTN_STAGE(t + 1, Ks[cur ^ 1], Vs[cur ^ 1]);
            asm volatile("s_waitcnt vmcnt(8)" ::: "memory");
        } else {
            asm volatile("s_waitcnt vmcnt(0)" ::: "memory");
        }
        __builtin_amdgcn_s_barrier();

        const unsigned short* Kbuf = Ks[cur];
        const unsigned short* Vbuf = Vs[cur];
        const int kb0 = t * 64;
        if (kb0 <= qw0 + 31) ATTN_TILE_BODY(Kbuf, Vbuf, kb0);
        __builtin_amdgcn_s_barrier();
    }

    if (np == 1) {
        float inv = 1.f / lrun;
        unsigned short* Op = O + ((size_t)(b * Sc + qg)) * Dc + h * HDc;
#pragma unroll
        for (int dc = 0; dc < 4; ++dc)
#pragma unroll
            for (int rg = 0; rg < 4; ++rg) {
                int d0 = 32 * dc + 8 * rg + 4 * Hh;
                u16x4 pk;
#pragma unroll
                for (int j = 0; j < 4; ++j) pk[j] = f2bf(accv[dc][rg * 4 + j] * inv);
                *(u16x4*)(Op + d0) = pk;
            }
    } else {
        const int jslot = ((bh << 3) + (qt - 8)) * 2 + part;
        unsigned short* pa = pacc + (size_t)jslot * (128 * 128) + (w * 32 + ql) * 128;
#pragma unroll
        for (int dc = 0; dc < 4; ++dc)
#pragma unroll
            for (int rg = 0; rg < 4; ++rg) {
                u16x4 pk;
#pragma unroll
                for (int j = 0; j < 4; ++j) pk[j] = f2bf(accv[dc][rg * 4 + j]);
                *(u16x4*)&pa[32 * dc + 8 * rg + 4 * Hh] = pk;
            }
        if (Hh == 0) {
            float* pm2 = pml + (size_t)jslot * 256 + (w * 32 + ql) * 2;
            pm2[0] = mrun; pm2[1] = lrun;
        }
    }
}

__global__ __launch_bounds__(256) void attn_combine(
    const unsigned short* __restrict__ pacc, const float* __restrict__ pml,
    unsigned short* __restrict__ O) {
    const int w = threadIdx.x >> 6, l = threadIdx.x & 63;
    const int idx = blockIdx.x * 4 + w;
    const int jp = idx >> 7, row = idx & 127;
    const int bh = jp >> 3, qt = (jp & 7) + 8;
    const int b = bh >> 4, h = bh & 15;
    const unsigned short* a0 = pacc + ((size_t)jp * 2) * (128 * 128) + row * 128;
    const unsigned short* a1 = a0 + 128 * 128;
    const float* ml0 = pml + ((size_t)jp * 2) * 256 + row * 2;
    const float* ml1 = ml0 + 256;
    float m0 = ml0[0], l0 = ml0[1], m1 = ml1[0], l1 = ml1[1];
    float M = fmaxf(m0, m1);
    float w0 = exp2f(m0 - M), w1 = exp2f(m1 - M);
    float inv = 1.f / (l0 * w0 + l1 * w1);
    int d = l * 2;
    u16x2 v0 = *(const u16x2*)&a0[d];
    u16x2 v1 = *(const u16x2*)&a1[d];
    u16x2 pk;
    pk[0] = f2bf((bf2f(v0[0]) * w0 + bf2f(v1[0]) * w1) * inv);
    pk[1] = f2bf((bf2f(v0[1]) * w0 + bf2f(v1[1]) * w1) * inv);
    int qrow = qt * 128 + row;
    *(u16x2*)(O + ((size_t)(b * Sc + qrow)) * Dc + h * HDc + d) = pk;
}

// --------------------------- attn fallback (R5, unsplit) ---------------------
__global__ __launch_bounds__(256, 2) void attn_fwd5(
    const unsigned short* __restrict__ Q, const unsigned short* __restrict__ Kb,
    const unsigned short* __restrict__ Vt, unsigned short* __restrict__ O) {
    __shared__ __align__(16) unsigned short Ks[2][64 * 128];
    __shared__ __align__(16) unsigned short Vs[2][128 * 64];
    const int tid = threadIdx.x;
    const int w = tid >> 6, l = tid & 63;
    const int ql = l & 31, Hh = l >> 5;
    const int bh = blockIdx.x;
    const int y = blockIdx.y;
    const int qt = (y < 8) ? y : (23 - y);
    const int b = bh >> 4, h = bh & 15;

    const unsigned short* Kbase = Kb + ((size_t)b * Sc) * Dc + h * HDc;
    const unsigned short* Vbase = Vt + ((size_t)b * Dc + h * HDc) * Sc;

    const int qw0 = qt * 128 + w * 32;
    const int qg = qw0 + ql;

    short8 qf[8];
    {
        const unsigned short* qp = Q + ((size_t)(b * Sc + qg)) * Dc + h * HDc;
#pragma unroll
        for (int dc = 0; dc < 8; ++dc)
            qf[dc] = *(const short8*)(qp + dc * 16 + Hh * 8);
    }
    f32x16 accv[4];
#pragma unroll
    for (int i = 0; i < 4; ++i) accv[i] = (f32x16)(0.f);
    float mrun = -3.0e38f, lrun = 0.f;
    const int nt = 2 * qt + 2;

    ATTN_STAGE(0, Ks[0], Vs[0]);
    for (int t = 0; t < nt; ++t) {
        if (t + 1 < nt) {
            ATTN_STAGE(t + 1, Ks[(t + 1) & 1], Vs[(t + 1) & 1]);
            asm volatile("s_waitcnt vmcnt(8)" ::: "memory");
        } else {
            asm volatile("s_waitcnt vmcnt(0)" ::: "memory");
        }
        __builtin_amdgcn_s_barrier();

        const unsigned short* Kbuf = Ks[t & 1];
        const unsigned short* Vbuf = Vs[t & 1];
        const int kb0 = t * 64;
        if (kb0 <= qw0 + 31) ATTN_TILE_BODY(Kbuf, Vbuf, kb0);
        __builtin_amdgcn_s_barrier();
    }
    float inv = 1.f / lrun;
    unsigned short* Op = O + ((size_t)(b * Sc + qg)) * Dc + h * HDc;
#pragma unroll
    for (int dc = 0; dc < 4; ++dc)
#pragma unroll
        for (int rg = 0; rg < 4; ++rg) {
            int d0 = 32 * dc + 8 * rg + 4 * Hh;
            u16x4 pk;
#pragma unroll
            for (int j = 0; j < 4; ++j) pk[j] = f2bf(accv[dc][rg * 4 + j] * inv);
            *(u16x4*)(Op + d0) = pk;
        }
}

// ------------------------------- launcher -----------------------------------
extern "C" void kernel_launch(void* const* d_in, const int* in_sizes, int n_in,
                              void* d_out, int out_size, void* d_ws, size_t ws_size,
                              hipStream_t stream) {
    const float* x  = (const float*)d_in[0];
    const float* wq = (const float*)d_in[1];
    const float* bq = (const float*)d_in[2];
    const float* wk = (const float*)d_in[3];
    const float* bk = (const float*)d_in[4];
    const float* wv = (const float*)d_in[5];
    const float* bv = (const float*)d_in[6];
    const float* wo = (const float*)d_in[7];
    const float* bo = (const float*)d_in[8];
    const float* rc = (const float*)d_in[9];
    const float* rs = (const float*)d_in[10];

    const size_t NE = (size_t)Mc * Dc;
    const size_t NW = (size_t)Dc * Dc;

    unsigned short* xb = (unsigned short*)d_ws;  // x bf16; reused as attn out
    unsigned short* qb = xb + NE;
    unsigned short* kb = qb + NE;
    unsigned short* vt = kb + NE;                // V^T [B][D][S]
    unsigned short* wb = vt + NE;                // weight buffer(s)

    const int ne8 = (int)(NE / 8), nw8 = (int)(NW / 8);
    dim3 tb(256);
    const bool big_ws = ws_size >= (4 * NE + 4 * NW) * sizeof(unsigned short);

    if (big_ws) {
        unsigned short* wqb = wb;                 // [wqb|wkb|wvb] = fused Wqkv
        unsigned short* wkb = wb + NW;
        unsigned short* wvb = wb + 2 * NW;
        unsigned short* wob = wb + 3 * NW;
        unsigned short* pacc = wb;                // dead wqb+wkb after QKV GEMM
        float* pml = (float*)(wb + 2 * NW);       // inside dead wvb
        cvt_batch<<<dim3(ne8 / 256, 5), tb, 0, stream>>>(
            x, xb, wq, wqb, wk, wkb, wv, wvb, wo, wob);
        gemm10<0><<<dim3(Nc * 3 / 128, Mc / 256), dim3(512), 0, stream>>>(
            xb, wb, bq, bk, bv, rc, rs, qb, kb, vt);
        attn_part<<<dim3(Bc * Hc, 24), tb, 0, stream>>>(qb, kb, vt, xb, pacc, pml);
        attn_combine<<<dim3(32 * 8 * 128 / 4), tb, 0, stream>>>(pacc, pml, xb);
        gemm10<1><<<dim3(Nc / 128, Mc / 256), dim3(512), 0, stream>>>(
            xb, wob, bo, nullptr, nullptr, rc, rs, d_out, nullptr, nullptr);
    } else {
        dim3 gg(Nc / 128, Mc / 128);
        cvt_f32_bf16<<<dim3(ne8 / 256), tb, 0, stream>>>(x, xb, ne8);
        cvt_f32_bf16<<<dim3(nw8 / 256), tb, 0, stream>>>(wq, wb, nw8);
        gemm_nt<0><<<gg, tb, 0, stream>>>(xb, wb, bq, rc, rs, qb);
        cvt_f32_bf16<<<dim3(nw8 / 256), tb, 0, stream>>>(wk, wb, nw8);
        gemm_nt<1><<<gg, tb, 0, stream>>>(xb, wb, bk, rc, rs, kb);
        cvt_f32_bf16<<<dim3(nw8 / 256), tb, 0, stream>>>(wv, wb, nw8);
        gemm_nt<2><<<gg, tb, 0, stream>>>(xb, wb, bv, rc, rs, vt);
        attn_fwd5<<<dim3(Bc * Hc, 16), tb, 0, stream>>>(qb, kb, vt, xb);
        cvt_f32_bf16<<<dim3(nw8 / 256), tb, 0, stream>>>(wo, wb, nw8);
        gemm_nt<3><<<gg, tb, 0, stream>>>(xb, wb, bo, rc, rs, d_out);
    }
}

// Round 11
// 248.662 us; speedup vs baseline: 1.1392x; 1.1392x over previous
//
#include <hip/hip_runtime.h>

// ---------------------------------------------------------------------------
// CasualMultiQueryAttention: x->(Q,K,V) proj + RoPE, causal flash attention,
// output projection. B=2,S=2048,D=2048,H=16,HD=128. bf16 MFMA compute.
// R11: revert GEMM to R9's proven gemm9 (best: 249us total). R10's single-
//      region experiment regressed (650 TF): barrier-locked waves burst
//      reads together -> no overlap. Adds two zero-risk trims: (a) hoisted
//      lane-constant LDS read offsets (R9 recomputed them each phase,
//      VGPR=88 => rematerialization), (b) exact 1D convert grid (12288 vs
//      20480 blocks). Attention/fallback identical to R7-R9 (proven).
// ---------------------------------------------------------------------------

typedef __attribute__((ext_vector_type(8))) short short8;
typedef __attribute__((ext_vector_type(4))) float f32x4;
typedef __attribute__((ext_vector_type(16))) float f32x16;
typedef __attribute__((ext_vector_type(2))) unsigned short u16x2;
typedef __attribute__((ext_vector_type(4))) unsigned short u16x4;
typedef __attribute__((ext_vector_type(8))) unsigned short u16x8;

constexpr int Bc = 2, Sc = 2048, Dc = 2048, Hc = 16, HDc = 128;
constexpr int Mc = Bc * Sc;            // 4096 rows
constexpr int Nc = Dc, Kc = Dc;        // 2048
constexpr int NT = Kc / 64;            // 32 K-tiles
constexpr float QSCL = 0.08838834764831845f * 1.4426950408889634f; // 1/sqrt(HD)*log2e

__device__ __forceinline__ unsigned short f2bf(float f) {
    union { float f; unsigned u; } x; x.f = f;
    unsigned r = x.u + 0x7FFFu + ((x.u >> 16) & 1u);   // RNE
    return (unsigned short)(r >> 16);
}
__device__ __forceinline__ float bf2f(unsigned short u) {
    union { float f; unsigned u; } x; x.u = (unsigned)u << 16; return x.f;
}

__device__ __forceinline__ void g2lds16(const void* g, void* l) {
    __builtin_amdgcn_global_load_lds(
        (const __attribute__((address_space(1))) void*)g,
        (__attribute__((address_space(3))) void*)l, 16, 0, 0);
}

// --------------------------- fp32 -> bf16 convert ---------------------------
__device__ __forceinline__ void cvt_body(const float* __restrict__ in,
                                         unsigned short* __restrict__ out, int i) {
    f32x4 a = *((const f32x4*)in + (size_t)i * 2);
    f32x4 b = *((const f32x4*)in + (size_t)i * 2 + 1);
    u16x8 o;
    o[0] = f2bf(a[0]); o[1] = f2bf(a[1]); o[2] = f2bf(a[2]); o[3] = f2bf(a[3]);
    o[4] = f2bf(b[0]); o[5] = f2bf(b[1]); o[6] = f2bf(b[2]); o[7] = f2bf(b[3]);
    *((u16x8*)out + i) = o;
}

__global__ __launch_bounds__(256) void cvt_f32_bf16(
    const float* __restrict__ in, unsigned short* __restrict__ out, int n8) {
    int i = blockIdx.x * 256 + threadIdx.x;
    if (i >= n8) return;
    cvt_body(in, out, i);
}

// Exact 1D grid: 4096 blocks for x (1048576 vec8s) + 4x2048 for weights.
__global__ __launch_bounds__(256) void cvt_all(
    const float* __restrict__ x,  unsigned short* __restrict__ xo,
    const float* __restrict__ w0, unsigned short* __restrict__ o0,
    const float* __restrict__ w1, unsigned short* __restrict__ o1,
    const float* __restrict__ w2, unsigned short* __restrict__ o2,
    const float* __restrict__ w3, unsigned short* __restrict__ o3) {
    int bid = blockIdx.x;
    const float* in; unsigned short* out;
    if (bid < 4096) { in = x; out = xo; }
    else {
        int r = bid - 4096, which = r >> 11;
        bid = r & 2047;
        if (which == 0)      { in = w0; out = o0; }
        else if (which == 1) { in = w1; out = o1; }
        else if (which == 2) { in = w2; out = o2; }
        else                 { in = w3; out = o3; }
    }
    cvt_body(in, out, bid * 256 + threadIdx.x);
}

// ------------------ 8-wave phase-interleaved GEMM (256x128) ------------------
// KIND 0: fused QKV. A[4096][2048]*Wqkv[6144][2048]^T; mode=n0>>11 selects
//         epilogue: 0 RoPE->q (QSCL), 1 RoPE->k, 2 ->V^T [B][D][S].
// KIND 1: out-proj. A=attn out; epilogue fp32 + bias -> oq (float*).
// Ring-3 LDS: stage tile t+2 while computing t; vmcnt(6) at tile boundary
// drains exactly tile t+1 (6 loads/tile/wave, fixed issue order).
// 2 phases per K-tile, 16 MFMA each; LDS read offsets hoisted (R11).
#define G9_STAGE_A(tt, rr, ii) {                                               \
    int s_ = (ii) * 512 + tid, row_ = s_ >> 3, c_ = s_ & 7;                    \
    g2lds16(A + (size_t)(m0 + row_) * Kc + (tt) * 64 + ((c_ ^ (row_ & 7)) << 3), \
            &As[rr][(size_t)((ii) * 512 + (w << 6)) * 8]); }
#define G9_STAGE_B(tt, rr, ii) {                                               \
    int s_ = (ii) * 512 + tid, row_ = s_ >> 3, c_ = s_ & 7;                    \
    g2lds16(W + (size_t)(n0 + row_) * Kc + (tt) * 64 + ((c_ ^ (row_ & 7)) << 3), \
            &Bs[rr][(size_t)((ii) * 512 + (w << 6)) * 8]); }
#define G9_RD(rr, kk) { _Pragma("unroll")                                      \
    for (int i = 0; i < 4; ++i) {                                              \
        af[i] = *(const short8*)((const char*)As[rr] + offA[kk][i]);           \
        bf[i] = *(const short8*)((const char*)Bs[rr] + offB[kk][i]); } }
#define G9_MFMA16 { _Pragma("unroll")                                          \
    for (int i = 0; i < 4; ++i)                                                \
        _Pragma("unroll")                                                      \
        for (int j = 0; j < 4; ++j)                                            \
            acc[i][j] = __builtin_amdgcn_mfma_f32_16x16x32_bf16(af[i], bf[j], acc[i][j], 0, 0, 0); }
#define G9_SYNC1 __builtin_amdgcn_s_barrier();                                 \
    asm volatile("s_waitcnt lgkmcnt(0)" ::: "memory");                         \
    __builtin_amdgcn_s_setprio(1);
#define G9_SYNC2 __builtin_amdgcn_s_setprio(0); __builtin_amdgcn_s_barrier();

template <int KIND>
__global__ __launch_bounds__(512, 2) void gemm9(
    const unsigned short* __restrict__ A, const unsigned short* __restrict__ W,
    const float* __restrict__ bq, const float* __restrict__ bk,
    const float* __restrict__ bv, const float* __restrict__ rc,
    const float* __restrict__ rs, void* __restrict__ oq,
    unsigned short* __restrict__ ok, unsigned short* __restrict__ ov) {
    __shared__ __align__(16) unsigned short As[3][256 * 64];   // 96 KB
    __shared__ __align__(16) unsigned short Bs[3][128 * 64];   // 48 KB
    const int tid = threadIdx.x;
    const int w = tid >> 6, l = tid & 63;
    const int wm = w >> 1, wn = w & 1;            // 4M x 2N waves
    const int lrow = l & 15, lhi = l >> 4;
    const int m0 = blockIdx.y * 256, n0 = blockIdx.x * 128;

    // hoisted lane-constant LDS read byte-offsets (R11)
    int offA[2][4], offB[2][4];
#pragma unroll
    for (int kk = 0; kk < 2; ++kk)
#pragma unroll
        for (int i = 0; i < 4; ++i) {
            int ra = wm * 64 + i * 16 + lrow;
            offA[kk][i] = (ra * 64 + (((kk * 4 + lhi) ^ (ra & 7)) << 3)) * 2;
            int rb = wn * 64 + i * 16 + lrow;
            offB[kk][i] = (rb * 64 + (((kk * 4 + lhi) ^ (rb & 7)) << 3)) * 2;
        }

    f32x4 acc[4][4];
#pragma unroll
    for (int i = 0; i < 4; ++i)
#pragma unroll
        for (int j = 0; j < 4; ++j) acc[i][j] = (f32x4){0.f, 0.f, 0.f, 0.f};

    // prologue: stage tiles 0,1 (order per tile: A0,A1,A2,A3,B0,B1)
#pragma unroll
    for (int ii = 0; ii < 4; ++ii) G9_STAGE_A(0, 0, ii);
    G9_STAGE_B(0, 0, 0); G9_STAGE_B(0, 0, 1);
#pragma unroll
    for (int ii = 0; ii < 4; ++ii) G9_STAGE_A(1, 1, ii);
    G9_STAGE_B(1, 1, 0); G9_STAGE_B(1, 1, 1);
    asm volatile("s_waitcnt vmcnt(6)" ::: "memory");   // tile 0 landed
    __builtin_amdgcn_s_barrier();

    short8 af[4], bf[4];
    for (int t = 0; t < NT; ++t) {
        const int r = t % 3, rn = (t + 2) % 3;
        const bool st = (t + 2) < NT;
        // P0: kk=0 frags (8 ds_read) | stage A0,A1,A2 of t+2 | 16 MFMA
        G9_RD(r, 0);
        if (st) { G9_STAGE_A(t + 2, rn, 0); G9_STAGE_A(t + 2, rn, 1); G9_STAGE_A(t + 2, rn, 2); }
        G9_SYNC1; G9_MFMA16; G9_SYNC2;
        // P1: kk=1 frags | stage A3,B0,B1 | boundary counted vmcnt | 16 MFMA
        G9_RD(r, 1);
        if (st) {
            G9_STAGE_A(t + 2, rn, 3); G9_STAGE_B(t + 2, rn, 0); G9_STAGE_B(t + 2, rn, 1);
            asm volatile("s_waitcnt vmcnt(6)" ::: "memory");   // t+1 landed
        } else {
            asm volatile("s_waitcnt vmcnt(0)" ::: "memory");
        }
        G9_SYNC1; G9_MFMA16; G9_SYNC2;
    }

    // ---- epilogue ----
    const int mode = (KIND == 1) ? 3 : (n0 >> 11);   // uniform per block
    const float* bias = (KIND == 1) ? bq : (mode == 0 ? bq : mode == 1 ? bk : bv);
#pragma unroll
    for (int i = 0; i < 4; ++i) {
#pragma unroll
        for (int j = 0; j < 4; ++j) {
            int gm0 = m0 + wm * 64 + i * 16 + lhi * 4;
            int gn  = n0 + wn * 64 + j * 16 + lrow;
            int gnl = gn & (Dc - 1);
            float bvv = bias[gnl];
            if (mode == 0 || mode == 1) {
                unsigned short* o = (unsigned short*)(mode == 0 ? oq : (void*)ok);
                int fi = (gn & (HDc - 1)) >> 1;
#pragma unroll
                for (int rr = 0; rr < 4; ++rr) {
                    int gm = gm0 + rr;
                    float v = acc[i][j][rr] + bvv;
                    float p = __shfl_xor(v, 1);          // partner column gn^1
                    int pos = gm & (Sc - 1);
                    float cz = rc[pos * (HDc / 2) + fi];
                    float sz = rs[pos * (HDc / 2) + fi];
                    float ovv = (gn & 1) ? (p * sz + v * cz) : (v * cz - p * sz);
                    if (mode == 0) ovv *= QSCL;
                    o[(size_t)gm * Dc + gnl] = f2bf(ovv);
                }
            } else if (mode == 2) {
                int b = gm0 >> 11, sb = gm0 & (Sc - 1);
                u16x4 pk;
#pragma unroll
                for (int rr = 0; rr < 4; ++rr) pk[rr] = f2bf(acc[i][j][rr] + bvv);
                *(u16x4*)&ov[((size_t)b * Dc + gnl) * Sc + sb] = pk;
            } else {
                float* o = (float*)oq;
#pragma unroll
                for (int rr = 0; rr < 4; ++rr)
                    o[(size_t)(gm0 + rr) * Nc + gn] = acc[i][j][rr] + bvv;
            }
        }
    }
}

// --------------------------- legacy 128^2 GEMM (fallback path) ---------------
template <int MODE>
__global__ __launch_bounds__(256) void gemm_nt(
    const unsigned short* __restrict__ A, const unsigned short* __restrict__ W,
    const float* __restrict__ bias, const float* __restrict__ rc,
    const float* __restrict__ rs, void* __restrict__ outp) {
    __shared__ __align__(16) unsigned short As[128 * 64];
    __shared__ __align__(16) unsigned short Bs[128 * 64];
    const int tid = threadIdx.x;
    const int w = tid >> 6, l = tid & 63;
    const int wm = w >> 1, wn = w & 1;
    const int lrow = l & 15, lhi = l >> 4;
    const int m0 = blockIdx.y * 128, n0 = blockIdx.x * 128;

    f32x4 acc[4][4];
#pragma unroll
    for (int i = 0; i < 4; ++i)
#pragma unroll
        for (int j = 0; j < 4; ++j) acc[i][j] = (f32x4){0.f, 0.f, 0.f, 0.f};

    for (int k0 = 0; k0 < Kc; k0 += 64) {
        __syncthreads();
#pragma unroll
        for (int i = 0; i < 4; ++i) {
            int s = i * 256 + tid;
            int row = s >> 3, c = s & 7;
            int cg = (c ^ (row & 7)) * 8;
            g2lds16(A + (size_t)(m0 + row) * Kc + k0 + cg,
                    &As[(size_t)(i * 256 + (w << 6)) * 8]);
            g2lds16(W + (size_t)(n0 + row) * Kc + k0 + cg,
                    &Bs[(size_t)(i * 256 + (w << 6)) * 8]);
        }
        __syncthreads();
#pragma unroll
        for (int kk = 0; kk < 2; ++kk) {
            short8 af[4], bf[4];
#pragma unroll
            for (int i = 0; i < 4; ++i) {
                int ra = wm * 64 + i * 16 + lrow;
                af[i] = *(const short8*)&As[ra * 64 + (((kk * 4 + lhi) ^ (ra & 7)) << 3)];
                int rb = wn * 64 + i * 16 + lrow;
                bf[i] = *(const short8*)&Bs[rb * 64 + (((kk * 4 + lhi) ^ (rb & 7)) << 3)];
            }
#pragma unroll
            for (int i = 0; i < 4; ++i)
#pragma unroll
                for (int j = 0; j < 4; ++j)
                    acc[i][j] = __builtin_amdgcn_mfma_f32_16x16x32_bf16(
                        af[i], bf[j], acc[i][j], 0, 0, 0);
        }
    }

#pragma unroll
    for (int i = 0; i < 4; ++i) {
#pragma unroll
        for (int j = 0; j < 4; ++j) {
            int gm0 = m0 + wm * 64 + i * 16 + lhi * 4;
            int gn  = n0 + wn * 64 + j * 16 + lrow;
            float bv = bias[gn];
            if (MODE == 0 || MODE == 1) {
                unsigned short* o = (unsigned short*)outp;
                int fi = (gn & (HDc - 1)) >> 1;
#pragma unroll
                for (int r = 0; r < 4; ++r) {
                    int gm = gm0 + r;
                    float v = acc[i][j][r] + bv;
                    float p = __shfl_xor(v, 1);
                    int pos = gm & (Sc - 1);
                    float cz = rc[pos * (HDc / 2) + fi];
                    float sz = rs[pos * (HDc / 2) + fi];
                    float ov = (gn & 1) ? (p * sz + v * cz) : (v * cz - p * sz);
                    if (MODE == 0) ov *= QSCL;
                    o[(size_t)gm * Nc + gn] = f2bf(ov);
                }
            } else if (MODE == 2) {
                unsigned short* o = (unsigned short*)outp;
                int b = gm0 >> 11, sb = gm0 & (Sc - 1);
                u16x4 pk;
#pragma unroll
                for (int r = 0; r < 4; ++r) pk[r] = f2bf(acc[i][j][r] + bv);
                *(u16x4*)&o[((size_t)b * Dc + gn) * Sc + sb] = pk;
            } else {
                float* o = (float*)outp;
#pragma unroll
                for (int r = 0; r < 4; ++r)
                    o[(size_t)(gm0 + r) * Nc + gn] = acc[i][j][r] + bv;
            }
        }
    }
}

// ---------------- shared attention macros (proven R5 body) -------------------
#define ATTN_STAGE(tt, kd, vd) {                                               \
    const unsigned short* Kt = Kbase + (size_t)(tt) * 64 * Dc;                 \
    const unsigned short* Vp = Vbase + (tt) * 64;                              \
    _Pragma("unroll")                                                          \
    for (int i_ = 0; i_ < 4; ++i_) {                                           \
        int p_ = i_ * 256 + tid;                                               \
        int rK = p_ >> 4, sK = p_ & 15;                                        \
        g2lds16(Kt + (size_t)rK * Dc + ((sK ^ (rK & 15)) << 3),                \
                (kd) + (i_ * 256 + (w << 6)) * 8);                             \
        int rV = p_ >> 3, sV = p_ & 7;                                         \
        g2lds16(Vp + (size_t)rV * Sc + ((sV ^ (rV & 7)) << 3),                 \
                (vd) + (i_ * 256 + (w << 6)) * 8);                             \
    } }

#define ATTN_PVSTEP(PC, HB, KS) {                                              \
    int X0, X1, Y0, Y1;                                                        \
    asm("v_cvt_pk_bf16_f32 %0, %1, %2" : "=v"(X0) : "v"(PC[HB+0]), "v"(PC[HB+1])); \
    asm("v_cvt_pk_bf16_f32 %0, %1, %2" : "=v"(X1) : "v"(PC[HB+2]), "v"(PC[HB+3])); \
    asm("v_cvt_pk_bf16_f32 %0, %1, %2" : "=v"(Y0) : "v"(PC[HB+4]), "v"(PC[HB+5])); \
    asm("v_cvt_pk_bf16_f32 %0, %1, %2" : "=v"(Y1) : "v"(PC[HB+6]), "v"(PC[HB+7])); \
    asm("v_permlane32_swap_b32 %0, %1" : "+v"(X0), "+v"(Y0));                  \
    asm("v_permlane32_swap_b32 %0, %1" : "+v"(X1), "+v"(Y1));                  \
    union { int i[4]; short8 s; } pf_;                                         \
    pf_.i[0] = X0; pf_.i[1] = X1; pf_.i[2] = Y0; pf_.i[3] = Y1;                \
    _Pragma("unroll")                                                          \
    for (int dc_ = 0; dc_ < 4; ++dc_) {                                        \
        int rr = 32 * dc_ + ql;                                                \
        short8 vf = *(const short8*)&Vbuf[rr * 64 + (((2*(KS)+Hh) ^ (rr & 7)) << 3)]; \
        accv[dc_] = __builtin_amdgcn_mfma_f32_32x32x16_bf16(vf, pf_.s, accv[dc_], 0, 0, 0); \
    } }

#define ATTN_TILE_BODY(Kbuf, Vbuf, kb0)                                        \
    {                                                                          \
        f32x16 a0 = (f32x16)(0.f), a1 = (f32x16)(0.f);                         \
        __builtin_amdgcn_s_setprio(1);                                         \
        _Pragma("unroll")                                                      \
        for (int dc = 0; dc < 8; ++dc) {                                       \
            int r0 = ql, r1 = 32 + ql, sl = dc * 2 + Hh;                       \
            short8 k0 = *(const short8*)&Kbuf[r0 * 128 + ((sl ^ (r0 & 15)) << 3)]; \
            short8 k1 = *(const short8*)&Kbuf[r1 * 128 + ((sl ^ (r1 & 15)) << 3)]; \
            a0 = __builtin_amdgcn_mfma_f32_32x32x16_bf16(k0, qf[dc], a0, 0, 0, 0); \
            a1 = __builtin_amdgcn_mfma_f32_32x32x16_bf16(k1, qf[dc], a1, 0, 0, 0); \
        }                                                                      \
        __builtin_amdgcn_s_setprio(0);                                         \
        if ((kb0) >= 2 * qt * 64) {                                            \
            _Pragma("unroll")                                                  \
            for (int r = 0; r < 16; ++r) {                                     \
                int kl = (r & 3) + 8 * (r >> 2) + 4 * Hh;                      \
                if ((kb0) + kl > qg)      a0[r] = -3.0e38f;                    \
                if ((kb0) + 32 + kl > qg) a1[r] = -3.0e38f;                    \
            }                                                                  \
        }                                                                      \
        float m8[8];                                                           \
        _Pragma("unroll")                                                      \
        for (int r = 0; r < 8; ++r)                                            \
            m8[r] = fmaxf(fmaxf(a0[r], a0[r + 8]), fmaxf(a1[r], a1[r + 8]));   \
        float m4a = fmaxf(m8[0], m8[1]), m4b = fmaxf(m8[2], m8[3]);            \
        float m4c = fmaxf(m8[4], m8[5]), m4d = fmaxf(m8[6], m8[7]);            \
        float pm = fmaxf(fmaxf(m4a, m4b), fmaxf(m4c, m4d));                    \
        pm = fmaxf(pm, __shfl_xor(pm, 32));                                    \
        if (!__all(pm - mrun <= 8.0f)) {                                       \
            float mnew = fmaxf(mrun, pm);                                      \
            float fs = exp2f(mrun - mnew);                                     \
            mrun = mnew;                                                       \
            lrun *= fs;                                                        \
            _Pragma("unroll")                                                  \
            for (int dc = 0; dc < 4; ++dc)                                     \
                _Pragma("unroll")                                              \
                for (int r = 0; r < 16; ++r) accv[dc][r] *= fs;                \
        }                                                                      \
        float p0[16], p1[16];                                                  \
        _Pragma("unroll")                                                      \
        for (int r = 0; r < 16; ++r) p0[r] = exp2f(a0[r] - mrun);              \
        _Pragma("unroll")                                                      \
        for (int r = 0; r < 16; ++r) p1[r] = exp2f(a1[r] - mrun);              \
        float s8[8];                                                           \
        _Pragma("unroll")                                                      \
        for (int r = 0; r < 8; ++r)                                            \
            s8[r] = (p0[r] + p0[r + 8]) + (p1[r] + p1[r + 8]);                 \
        float s4a = s8[0] + s8[1], s4b = s8[2] + s8[3];                        \
        float s4c = s8[4] + s8[5], s4d = s8[6] + s8[7];                        \
        float ps = (s4a + s4b) + (s4c + s4d);                                  \
        lrun += ps + __shfl_xor(ps, 32);                                       \
        __builtin_amdgcn_s_setprio(1);                                         \
        ATTN_PVSTEP(p0, 0, 0); ATTN_PVSTEP(p0, 8, 1);                          \
        ATTN_PVSTEP(p1, 0, 2); ATTN_PVSTEP(p1, 8, 3);                          \
        __builtin_amdgcn_s_setprio(0);                                         \
    }

// --------------------------- attn: balanced KV-split part --------------------
__global__ __launch_bounds__(256, 2) void attn_part(
    const unsigned short* __restrict__ Q, const unsigned short* __restrict__ Kb,
    const unsigned short* __restrict__ Vt, unsigned short* __restrict__ O,
    unsigned short* __restrict__ pacc, float* __restrict__ pml) {
    __shared__ __align__(16) unsigned short Ks[2][64 * 128];
    __shared__ __align__(16) unsigned short Vs[2][128 * 64];
    const int tid = threadIdx.x;
    const int w = tid >> 6, l = tid & 63;
    const int ql = l & 31, Hh = l >> 5;
    const int bh = blockIdx.x;
    const int slot = blockIdx.y;
    int qt, part, np;
    if (slot < 16) { qt = 15 - (slot >> 1); part = slot & 1; np = 2; }
    else           { qt = 23 - slot;        part = 0;        np = 1; }
    const int nt   = 2 * qt + 2;
    const int tbeg = part ? (qt + 1) : 0;
    const int tend = (np == 2 && part == 0) ? (qt + 1) : nt;
    const int b = bh >> 4, h = bh & 15;

    const unsigned short* Kbase = Kb + ((size_t)b * Sc) * Dc + h * HDc;
    const unsigned short* Vbase = Vt + ((size_t)b * Dc + h * HDc) * Sc;

    const int qw0 = qt * 128 + w * 32;
    const int qg = qw0 + ql;

    short8 qf[8];
    {
        const unsigned short* qp = Q + ((size_t)(b * Sc + qg)) * Dc + h * HDc;
#pragma unroll
        for (int dc = 0; dc < 8; ++dc)
            qf[dc] = *(const short8*)(qp + dc * 16 + Hh * 8);
    }
    f32x16 accv[4];
#pragma unroll
    for (int i = 0; i < 4; ++i) accv[i] = (f32x16)(0.f);
    float mrun = -3.0e38f, lrun = 0.f;

    ATTN_STAGE(tbeg, Ks[0], Vs[0]);
    for (int t = tbeg; t < tend; ++t) {
        const int cur = (t - tbeg) & 1;
        if (t + 1 < tend) {
            ATTN_STAGE(t + 1, Ks[cur ^ 1], Vs[cur ^ 1]);
            asm volatile("s_waitcnt vmcnt(8)" ::: "memory");
        } else {
            asm volatile("s_waitcnt vmcnt(0)" ::: "memory");
        }
        __builtin_amdgcn_s_barrier();

        const unsigned short* Kbuf = Ks[cur];
        const unsigned short* Vbuf = Vs[cur];
        const int kb0 = t * 64;
        if (kb0 <= qw0 + 31) ATTN_TILE_BODY(Kbuf, Vbuf, kb0);
        __builtin_amdgcn_s_barrier();
    }

    if (np == 1) {
        float inv = 1.f / lrun;
        unsigned short* Op = O + ((size_t)(b * Sc + qg)) * Dc + h * HDc;
#pragma unroll
        for (int dc = 0; dc < 4; ++dc)
#pragma unroll
            for (int rg = 0; rg < 4; ++rg) {
                int d0 = 32 * dc + 8 * rg + 4 * Hh;
                u16x4 pk;
#pragma unroll
                for (int j = 0; j < 4; ++j) pk[j] = f2bf(accv[dc][rg * 4 + j] * inv);
                *(u16x4*)(Op + d0) = pk;
            }
    } else {
        const int jslot = ((bh << 3) + (qt - 8)) * 2 + part;
        unsigned short* pa = pacc + (size_t)jslot * (128 * 128) + (w * 32 + ql) * 128;
#pragma unroll
        for (int dc = 0; dc < 4; ++dc)
#pragma unroll
            for (int rg = 0; rg < 4; ++rg) {
                u16x4 pk;
#pragma unroll
                for (int j = 0; j < 4; ++j) pk[j] = f2bf(accv[dc][rg * 4 + j]);
                *(u16x4*)&pa[32 * dc + 8 * rg + 4 * Hh] = pk;
            }
        if (Hh == 0) {
            float* pm2 = pml + (size_t)jslot * 256 + (w * 32 + ql) * 2;
            pm2[0] = mrun; pm2[1] = lrun;
        }
    }
}

__global__ __launch_bounds__(256) void attn_combine(
    const unsigned short* __restrict__ pacc, const float* __restrict__ pml,
    unsigned short* __restrict__ O) {
    const int w = threadIdx.x >> 6, l = threadIdx.x & 63;
    const int idx = blockIdx.x * 4 + w;
    const int jp = idx >> 7, row = idx & 127;
    const int bh = jp >> 3, qt = (jp & 7) + 8;
    const int b = bh >> 4, h = bh & 15;
    const unsigned short* a0 = pacc + ((size_t)jp * 2) * (128 * 128) + row * 128;
    const unsigned short* a1 = a0 + 128 * 128;
    const float* ml0 = pml + ((size_t)jp * 2) * 256 + row * 2;
    const float* ml1 = ml0 + 256;
    float m0 = ml0[0], l0 = ml0[1], m1 = ml1[0], l1 = ml1[1];
    float M = fmaxf(m0, m1);
    float w0 = exp2f(m0 - M), w1 = exp2f(m1 - M);
    float inv = 1.f / (l0 * w0 + l1 * w1);
    int d = l * 2;
    u16x2 v0 = *(const u16x2*)&a0[d];
    u16x2 v1 = *(const u16x2*)&a1[d];
    u16x2 pk;
    pk[0] = f2bf((bf2f(v0[0]) * w0 + bf2f(v1[0]) * w1) * inv);
    pk[1] = f2bf((bf2f(v0[1]) * w0 + bf2f(v1[1]) * w1) * inv);
    int qrow = qt * 128 + row;
    *(u16x2*)(O + ((size_t)(b * Sc + qrow)) * Dc + h * HDc + d) = pk;
}

// --------------------------- attn fallback (R5, unsplit) ---------------------
__global__ __launch_bounds__(256, 2) void attn_fwd5(
    const unsigned short* __restrict__ Q, const unsigned short* __restrict__ Kb,
    const unsigned short* __restrict__ Vt, unsigned short* __restrict__ O) {
    __shared__ __align__(16) unsigned short Ks[2][64 * 128];
    __shared__ __align__(16) unsigned short Vs[2][128 * 64];
    const int tid = threadIdx.x;
    const int w = tid >> 6, l = tid & 63;
    const int ql = l & 31, Hh = l >> 5;
    const int bh = blockIdx.x;
    const int y = blockIdx.y;
    const int qt = (y < 8) ? y : (23 - y);
    const int b = bh >> 4, h = bh & 15;

    const unsigned short* Kbase = Kb + ((size_t)b * Sc) * Dc + h * HDc;
    const unsigned short* Vbase = Vt + ((size_t)b * Dc + h * HDc) * Sc;

    const int qw0 = qt * 128 + w * 32;
    const int qg = qw0 + ql;

    short8 qf[8];
    {
        const unsigned short* qp = Q + ((size_t)(b * Sc + qg)) * Dc + h * HDc;
#pragma unroll
        for (int dc = 0; dc < 8; ++dc)
            qf[dc] = *(const short8*)(qp + dc * 16 + Hh * 8);
    }
    f32x16 accv[4];
#pragma unroll
    for (int i = 0; i < 4; ++i) accv[i] = (f32x16)(0.f);
    float mrun = -3.0e38f, lrun = 0.f;
    const int nt = 2 * qt + 2;

    ATTN_STAGE(0, Ks[0], Vs[0]);
    for (int t = 0; t < nt; ++t) {
        if (t + 1 < nt) {
            ATTN_STAGE(t + 1, Ks[(t + 1) & 1], Vs[(t + 1) & 1]);
            asm volatile("s_waitcnt vmcnt(8)" ::: "memory");
        } else {
            asm volatile("s_waitcnt vmcnt(0)" ::: "memory");
        }
        __builtin_amdgcn_s_barrier();

        const unsigned short* Kbuf = Ks[t & 1];
        const unsigned short* Vbuf = Vs[t & 1];
        const int kb0 = t * 64;
        if (kb0 <= qw0 + 31) ATTN_TILE_BODY(Kbuf, Vbuf, kb0);
        __builtin_amdgcn_s_barrier();
    }
    float inv = 1.f / lrun;
    unsigned short* Op = O + ((size_t)(b * Sc + qg)) * Dc + h * HDc;
#pragma unroll
    for (int dc = 0; dc < 4; ++dc)
#pragma unroll
        for (int rg = 0; rg < 4; ++rg) {
            int d0 = 32 * dc + 8 * rg + 4 * Hh;
            u16x4 pk;
#pragma unroll
            for (int j = 0; j < 4; ++j) pk[j] = f2bf(accv[dc][rg * 4 + j] * inv);
            *(u16x4*)(Op + d0) = pk;
        }
}

// ------------------------------- launcher -----------------------------------
extern "C" void kernel_launch(void* const* d_in, const int* in_sizes, int n_in,
                              void* d_out, int out_size, void* d_ws, size_t ws_size,
                              hipStream_t stream) {
    const float* x  = (const float*)d_in[0];
    const float* wq = (const float*)d_in[1];
    const float* bq = (const float*)d_in[2];
    const float* wk = (const float*)d_in[3];
    const float* bk = (const float*)d_in[4];
    const float* wv = (const float*)d_in[5];
    const float* bv = (const float*)d_in[6];
    const float* wo = (const float*)d_in[7];
    const float* bo = (const float*)d_in[8];
    const float* rc = (const float*)d_in[9];
    const float* rs = (const float*)d_in[10];

    const size_t NE = (size_t)Mc * Dc;
    const size_t NW = (size_t)Dc * Dc;

    unsigned short* xb = (unsigned short*)d_ws;  // x bf16; reused as attn out
    unsigned short* qb = xb + NE;
    unsigned short* kb = qb + NE;
    unsigned short* vt = kb + NE;                // V^T [B][D][S]
    unsigned short* wb = vt + NE;                // weight buffer(s)

    const int ne8 = (int)(NE / 8), nw8 = (int)(NW / 8);
    dim3 tb(256);
    const bool big_ws = ws_size >= (4 * NE + 4 * NW) * sizeof(unsigned short);

    if (big_ws) {
        unsigned short* wqb = wb;                 // [wqb|wkb|wvb] = fused Wqkv
        unsigned short* wkb = wb + NW;
        unsigned short* wvb = wb + 2 * NW;
        unsigned short* wob = wb + 3 * NW;
        unsigned short* pacc = wb;                // dead wqb+wkb after QKV GEMM
        float* pml = (float*)(wb + 2 * NW);       // inside dead wvb
        cvt_all<<<dim3(4096 + 4 * 2048), tb, 0, stream>>>(
            x, xb, wq, wqb, wk, wkb, wv, wvb, wo, wob);
        gemm9<0><<<dim3(Nc * 3 / 128, Mc / 256), dim3(512), 0, stream>>>(
            xb, wb, bq, bk, bv, rc, rs, qb, kb, vt);
        attn_part<<<dim3(Bc * Hc, 24), tb, 0, stream>>>(qb, kb, vt, xb, pacc, pml);
        attn_combine<<<dim3(32 * 8 * 128 / 4), tb, 0, stream>>>(pacc, pml, xb);
        gemm9<1><<<dim3(Nc / 128, Mc / 256), dim3(512), 0, stream>>>(
            xb, wob, bo, nullptr, nullptr, rc, rs, d_out, nullptr, nullptr);
    } else {
        dim3 gg(Nc / 128, Mc / 128);
        cvt_f32_bf16<<<dim3(ne8 / 256), tb, 0, stream>>>(x, xb, ne8);
        cvt_f32_bf16<<<dim3(nw8 / 256), tb, 0, stream>>>(wq, wb, nw8);
        gemm_nt<0><<<gg, tb, 0, stream>>>(xb, wb, bq, rc, rs, qb);
        cvt_f32_bf16<<<dim3(nw8 / 256), tb, 0, stream>>>(wk, wb, nw8);
        gemm_nt<1><<<gg, tb, 0, stream>>>(xb, wb, bk, rc, rs, kb);
        cvt_f32_bf16<<<dim3(nw8 / 256), tb, 0, stream>>>(wv, wb, nw8);
        gemm_nt<2><<<gg, tb, 0, stream>>>(xb, wb, bv, rc, rs, vt);
        attn_fwd5<<<dim3(Bc * Hc, 16), tb, 0, stream>>>(qb, kb, vt, xb);
        cvt_f32_bf16<<<dim3(nw8 / 256), tb, 0, stream>>>(wo, wb, nw8);
        gemm_nt<3><<<gg, tb, 0, stream>>>(xb, wb, bo, rc, rs, d_out);
    }
}